// Round 2
// baseline (192.404 us; speedup 1.0000x reference)
//
#include <hip/hip_runtime.h>

// WeightNet: y[n,c] = leakyrelu( sum_k pos[n,k] * W[seq[n],k,c] + b[seq[n],c] )
// N=500000, FANIN=7, C=64, L=2048. Memory-bound: 128 MB output write dominates.
// Layout: 16 threads/sample, each owns 4 consecutive channels (float4).
// A 64-lane wave covers 4 samples x 64 channels = 1 KiB contiguous store.

typedef float f32x4 __attribute__((ext_vector_type(4)));

#define FANIN 7
#define C 64
#define NEG_SLOPE 0.2f

__global__ __launch_bounds__(256) void weightnet_kernel(
    const float* __restrict__ pos,   // [N,7]
    const int*   __restrict__ seq,   // [N]
    const float* __restrict__ W,     // [L,7,64]
    const float* __restrict__ B,     // [L,64]
    float*       __restrict__ out,   // [N,64]
    int n_total)
{
    long gid = (long)blockIdx.x * 256 + threadIdx.x;
    if (gid >= (long)n_total * 16) return;
    int n  = (int)(gid >> 4);
    int c  = ((int)gid & 15) << 2;   // channel offset 0,4,...,60

    int idx = seq[n];

    // pos row (28 B, broadcast across the 16 lanes sharing this sample)
    const float* pn = pos + (size_t)n * FANIN;
    float p[FANIN];
    #pragma unroll
    for (int k = 0; k < FANIN; ++k) p[k] = pn[k];

    // gathered weight column block [7][4] + bias (L2/L3-resident: W is 3.67 MB)
    const f32x4* Wp = (const f32x4*)(W + (size_t)idx * (FANIN * C) + c);
    f32x4 acc = *(const f32x4*)(B + (size_t)idx * C + c);
    #pragma unroll
    for (int k = 0; k < FANIN; ++k) {
        f32x4 w = Wp[(size_t)k * (C / 4)];
        acc += p[k] * w;
    }

    // LeakyReLU
    acc.x = acc.x >= 0.f ? acc.x : NEG_SLOPE * acc.x;
    acc.y = acc.y >= 0.f ? acc.y : NEG_SLOPE * acc.y;
    acc.z = acc.z >= 0.f ? acc.z : NEG_SLOPE * acc.z;
    acc.w = acc.w >= 0.f ? acc.w : NEG_SLOPE * acc.w;

    // Streaming 128 MB output: nontemporal so it doesn't evict W from L2.
    __builtin_nontemporal_store(acc, (f32x4*)(out + (size_t)n * C + c));
}

extern "C" void kernel_launch(void* const* d_in, const int* in_sizes, int n_in,
                              void* d_out, int out_size, void* d_ws, size_t ws_size,
                              hipStream_t stream) {
    const float* pos = (const float*)d_in[0];
    const int*   seq = (const int*)d_in[1];
    const float* W   = (const float*)d_in[2];
    const float* B   = (const float*)d_in[3];
    float* out = (float*)d_out;

    int n_total = in_sizes[1];               // N (seq_idx element count)
    long total_threads = (long)n_total * 16;
    int blocks = (int)((total_threads + 255) / 256);
    weightnet_kernel<<<blocks, 256, 0, stream>>>(pos, seq, W, B, out, n_total);
}

// Round 3
// 187.140 us; speedup vs baseline: 1.0281x; 1.0281x over previous
//
#include <hip/hip_runtime.h>

// WeightNet: y[n,c] = leakyrelu( sum_k pos[n,k] * W[seq[n],k,c] + b[seq[n],c] )
// N=500000, FANIN=7, C=64, L=2048.
// R3 layout: 8 lanes/sample, each lane owns channels [4j,4j+3] and [4j+32,4j+35].
// pos/seq loaded coalesced once per wave (lanes 0..55 / 0..7), distributed by __shfl.
// Wave = 8 samples; stores cover full 128B cache lines. Output is nontemporal
// (128 MB stream, don't evict L2-resident W: 3.67 MB).

typedef float f32x4 __attribute__((ext_vector_type(4)));

#define FANIN 7
#define C 64
#define NEG_SLOPE 0.2f

__device__ __forceinline__ f32x4 lrelu4(f32x4 a) {
    a.x = a.x >= 0.f ? a.x : NEG_SLOPE * a.x;
    a.y = a.y >= 0.f ? a.y : NEG_SLOPE * a.y;
    a.z = a.z >= 0.f ? a.z : NEG_SLOPE * a.z;
    a.w = a.w >= 0.f ? a.w : NEG_SLOPE * a.w;
    return a;
}

__global__ __launch_bounds__(256) void weightnet_kernel(
    const float* __restrict__ pos,   // [N,7]
    const int*   __restrict__ seq,   // [N]
    const float* __restrict__ W,     // [L,7,64]
    const float* __restrict__ B,     // [L,64]
    float*       __restrict__ out,   // [N,64]
    int n_total)
{
    int tid  = threadIdx.x;
    int lane = tid & 63;
    int grp  = lane >> 3;            // sample within wave [0,8)
    int sub  = lane & 7;             // lane within sample [0,8)

    long wave_id = (long)blockIdx.x * 4 + (tid >> 6);
    long n_base  = wave_id * 8;      // first sample this wave handles
    int  n       = (int)(n_base + grp);

    // --- coalesced per-wave input staging ---
    // pos: 8 samples x 7 floats = 56 contiguous floats, lanes 0..55
    float pv = 0.f;
    long pofs = n_base * FANIN + lane;
    if (lane < 56 && pofs < (long)n_total * FANIN) pv = pos[pofs];
    // seq: 8 contiguous ints, lanes 0..7
    int sv = 0;
    if (lane < 8 && n_base + lane < n_total) sv = seq[n_base + lane];

    int idx = __shfl(sv, grp, 64);
    float p[FANIN];
    #pragma unroll
    for (int k = 0; k < FANIN; ++k) p[k] = __shfl(pv, grp * FANIN + k, 64);

    if (n >= n_total) return;

    int c = sub << 2;                // 0,4,...,28
    const float* Wn = W + (size_t)idx * (FANIN * C);
    const float* Bn = B + (size_t)idx * C;

    f32x4 acc0 = *(const f32x4*)(Bn + c);
    f32x4 acc1 = *(const f32x4*)(Bn + c + 32);
    #pragma unroll
    for (int k = 0; k < FANIN; ++k) {
        f32x4 w0 = *(const f32x4*)(Wn + k * C + c);
        f32x4 w1 = *(const f32x4*)(Wn + k * C + c + 32);
        acc0 += p[k] * w0;
        acc1 += p[k] * w1;
    }

    acc0 = lrelu4(acc0);
    acc1 = lrelu4(acc1);

    float* on = out + (size_t)n * C;
    __builtin_nontemporal_store(acc0, (f32x4*)(on + c));
    __builtin_nontemporal_store(acc1, (f32x4*)(on + c + 32));
}

extern "C" void kernel_launch(void* const* d_in, const int* in_sizes, int n_in,
                              void* d_out, int out_size, void* d_ws, size_t ws_size,
                              hipStream_t stream) {
    const float* pos = (const float*)d_in[0];
    const int*   seq = (const int*)d_in[1];
    const float* W   = (const float*)d_in[2];
    const float* B   = (const float*)d_in[3];
    float* out = (float*)d_out;

    int n_total = in_sizes[1];               // N (seq_idx element count)
    // 8 lanes/sample, 256-thread blocks -> 32 samples per block
    int blocks = (n_total + 31) / 32;
    weightnet_kernel<<<blocks, 256, 0, stream>>>(pos, seq, W, B, out, n_total);
}